// Round 3
// baseline (301.783 us; speedup 1.0000x reference)
//
#include <hip/hip_runtime.h>
#include <math.h>

#define H 1024
#define S 32768

typedef float f4 __attribute__((ext_vector_type(4)));

// ws layout (floats):
// [0,1024)       v = W^T @ hidden            (zeroed by memset)
// [1024]         completion counter (int)    (zeroed by same memset)
// [1028,3076)    per-block max partials (K2 grid = 2048)
// [3076,5124)    per-block sumexp partials
// [5124,5126)    M, invSum (written by K2's last block)
// energies live in d_out (finalized in-place by K4)

// K1: v[h] = sum_d W[d*H+h] * hidden[d].
// grid (4, 64): x = column group of 256, y = d-group of 16 rows.
__global__ __launch_bounds__(256) void compute_v(const float* __restrict__ W,
                                                 const float* __restrict__ hidden,
                                                 float* __restrict__ v) {
    int h = blockIdx.x * 256 + threadIdx.x;
    int d0 = blockIdx.y * 16;
    float acc = 0.f;
#pragma unroll
    for (int j = 0; j < 16; ++j) {
        int d = d0 + j;
        acc += W[(size_t)d * H + h] * hidden[d];  // coalesced across lanes
    }
    atomicAdd(&v[h], acc);
}

// K2: energies[s] = enc[s,:] . v ; per-block (max, sumexp) partials; the last
// block to finish reduces all partials into MS = {M, 1/Sum} (no spin, no
// co-residency assumption). 4 waves/block, 4 rows/wave -> 16 rows/block,
// grid = S/16 = 2048.
__global__ __launch_bounds__(256) void energies_kernel(const float* __restrict__ enc,
                                                       const float* __restrict__ v,
                                                       float* __restrict__ energies,
                                                       float* __restrict__ pmax,
                                                       float* __restrict__ psum,
                                                       int* __restrict__ counter,
                                                       float* __restrict__ MS) {
    const int lane = threadIdx.x & 63;
    const int wave = threadIdx.x >> 6;

    const f4* v4 = (const f4*)v;
    f4 va = v4[lane];
    f4 vb = v4[64 + lane];
    f4 vc = v4[128 + lane];
    f4 vd = v4[192 + lane];

    const int s0 = blockIdx.x * 16 + wave * 4;
    const f4* base = (const f4*)(enc + (size_t)s0 * H);

    float dot[4];
#pragma unroll
    for (int r = 0; r < 4; ++r) {
        const f4* row = base + r * (H / 4);
        f4 a = __builtin_nontemporal_load(row + lane);        // enc streamed once:
        f4 b = __builtin_nontemporal_load(row + 64 + lane);   // nt -> don't pollute L2
        f4 c = __builtin_nontemporal_load(row + 128 + lane);
        f4 d = __builtin_nontemporal_load(row + 192 + lane);
        float t = a.x * va.x + a.y * va.y + a.z * va.z + a.w * va.w;
        t += b.x * vb.x + b.y * vb.y + b.z * vb.z + b.w * vb.w;
        t += c.x * vc.x + c.y * vc.y + c.z * vc.z + c.w * vc.w;
        t += d.x * vd.x + d.y * vd.y + d.z * vd.z + d.w * vd.w;
        dot[r] = t;
    }

    // 4 interleaved butterfly reductions (all lanes end with full sums)
#pragma unroll
    for (int off = 32; off > 0; off >>= 1) {
#pragma unroll
        for (int r = 0; r < 4; ++r) dot[r] += __shfl_xor(dot[r], off, 64);
    }

    if (lane == 0) {
        float4 e = make_float4(dot[0], dot[1], dot[2], dot[3]);
        *(float4*)(energies + s0) = e;
    }

    float m = fmaxf(fmaxf(dot[0], dot[1]), fmaxf(dot[2], dot[3]));
    float sum = __expf(dot[0] - m) + __expf(dot[1] - m) +
                __expf(dot[2] - m) + __expf(dot[3] - m);

    __shared__ float wm[4], wsum[4];
    __shared__ int is_last;
    if (lane == 0) { wm[wave] = m; wsum[wave] = sum; }
    __syncthreads();
    if (threadIdx.x == 0) {
        float M = wm[0], Sm = wsum[0];
#pragma unroll
        for (int w = 1; w < 4; ++w) {
            float Mn = fmaxf(M, wm[w]);
            Sm = Sm * __expf(M - Mn) + wsum[w] * __expf(wm[w] - Mn);
            M = Mn;
        }
        pmax[blockIdx.x] = M;
        psum[blockIdx.x] = Sm;
        __threadfence();                       // release partials
        int ret = atomicAdd(counter, 1);       // device-scope
        is_last = (ret == (int)gridDim.x - 1);
    }
    __syncthreads();

    if (is_last) {                             // exactly one block runs this
        __threadfence();                       // acquire all partials
        const int tid = threadIdx.x;
        float M = -INFINITY, Sv = 0.f;
#pragma unroll
        for (int i = tid; i < 2048; i += 256) {
            float mi = pmax[i], si = psum[i];
            float Mn = fmaxf(M, mi);
            Sv = Sv * __expf(M - Mn) + si * __expf(mi - Mn);
            M = Mn;
        }
#pragma unroll
        for (int off = 32; off > 0; off >>= 1) {
            float Mo = __shfl_xor(M, off, 64);
            float So = __shfl_xor(Sv, off, 64);
            float Mn = fmaxf(M, Mo);
            Sv = Sv * __expf(M - Mn) + So * __expf(Mo - Mn);
            M = Mn;
        }
        if (lane == 0) { wm[wave] = M; wsum[wave] = Sv; }
        __syncthreads();
        if (tid == 0) {
            float Mf = wm[0], Sf = wsum[0];
#pragma unroll
            for (int w = 1; w < 4; ++w) {
                float Mn = fmaxf(Mf, wm[w]);
                Sf = Sf * __expf(Mf - Mn) + wsum[w] * __expf(wm[w] - Mn);
                Mf = Mn;
            }
            MS[0] = Mf;
            MS[1] = 1.0f / Sf;
        }
    }
}

// K4: out[i] = exp(e[i]-M) * invSum, in-place on d_out, float4.
__global__ __launch_bounds__(256) void finalize(float* __restrict__ out,
                                                const float* __restrict__ MS) {
    int i = blockIdx.x * 256 + threadIdx.x;
    float M = MS[0];
    float inv = MS[1];
    float4 e = ((const float4*)out)[i];
    float4 o;
    o.x = __expf(e.x - M) * inv;
    o.y = __expf(e.y - M) * inv;
    o.z = __expf(e.z - M) * inv;
    o.w = __expf(e.w - M) * inv;
    ((float4*)out)[i] = o;
}

extern "C" void kernel_launch(void* const* d_in, const int* in_sizes, int n_in,
                              void* d_out, int out_size, void* d_ws, size_t ws_size,
                              hipStream_t stream) {
    const float* hidden = (const float*)d_in[0];   // [H]
    const float* enc    = (const float*)d_in[1];   // [S,H]
    const float* W      = (const float*)d_in[2];   // [H,H]
    // d_in[3] = b: softmax is shift-invariant -> b contributes a constant, skip it.

    float* ws      = (float*)d_ws;
    float* v       = ws;            // 1024
    int*   counter = (int*)(ws + 1024);
    float* pmax    = ws + 1028;     // 2048
    float* psum    = ws + 3076;     // 2048
    float* MS      = ws + 5124;     // 2
    float* out     = (float*)d_out; // energies scratch, then probabilities

    hipMemsetAsync(ws, 0, (1024 + 4) * sizeof(float), stream);  // v + counter
    compute_v<<<dim3(4, 64), 256, 0, stream>>>(W, hidden, v);
    energies_kernel<<<S / 16, 256, 0, stream>>>(enc, v, out, pmax, psum, counter, MS);
    finalize<<<S / 4 / 256, 256, 0, stream>>>(out, MS);
}

// Round 4
// 204.571 us; speedup vs baseline: 1.4752x; 1.4752x over previous
//
#include <hip/hip_runtime.h>
#include <math.h>

#define H 1024
#define S 32768

typedef float f4 __attribute__((ext_vector_type(4)));

// ws layout (floats):
// [0,1024)      v = W^T @ hidden
// [1024,3072)   per-block max partials (K2 grid = 2048 blocks)
// [3072,5120)   per-block sumexp partials
// [5120,5122)   M, invSum
// energies live in d_out (finalized in-place by K4)

// K1: v[h] = sum_d W[d*H+h] * hidden[d].
// grid (4, 64): x = column group of 256, y = d-group of 16 rows.
__global__ __launch_bounds__(256) void compute_v(const float* __restrict__ W,
                                                 const float* __restrict__ hidden,
                                                 float* __restrict__ v) {
    int h = blockIdx.x * 256 + threadIdx.x;
    int d0 = blockIdx.y * 16;
    float acc = 0.f;
#pragma unroll
    for (int j = 0; j < 16; ++j) {
        int d = d0 + j;
        acc += W[(size_t)d * H + h] * hidden[d];  // coalesced across lanes
    }
    atomicAdd(&v[h], acc);
}

// K2: energies[s] = enc[s,:] . v ; per-block (max, sumexp) partials.
// 4 waves/block, 4 rows/wave -> 16 rows/block, grid = S/16 = 2048.
// ALL 16 float4 loads are issued into distinct registers before any FMA
// (R2's VGPR_Count=32 showed the compiler serialized rows with vmcnt(0)
// between them; hoisting keeps 16 KB/wave in flight).
__global__ __launch_bounds__(256) void energies_kernel(const float* __restrict__ enc,
                                                       const float* __restrict__ v,
                                                       float* __restrict__ energies,
                                                       float* __restrict__ pmax,
                                                       float* __restrict__ psum) {
    const int lane = threadIdx.x & 63;
    const int wave = threadIdx.x >> 6;

    const f4* v4 = (const f4*)v;
    f4 va = v4[lane];
    f4 vb = v4[64 + lane];
    f4 vc = v4[128 + lane];
    f4 vd = v4[192 + lane];

    const int s0 = blockIdx.x * 16 + wave * 4;
    const f4* base = (const f4*)(enc + (size_t)s0 * H);

    // issue all 16 loads first
    f4 a0 = base[lane],                 b0 = base[64 + lane];
    f4 c0 = base[128 + lane],           d0 = base[192 + lane];
    const f4* r1 = base + (H / 4);
    f4 a1 = r1[lane],                   b1 = r1[64 + lane];
    f4 c1 = r1[128 + lane],             d1 = r1[192 + lane];
    const f4* r2 = base + 2 * (H / 4);
    f4 a2 = r2[lane],                   b2 = r2[64 + lane];
    f4 c2 = r2[128 + lane],             d2 = r2[192 + lane];
    const f4* r3 = base + 3 * (H / 4);
    f4 a3 = r3[lane],                   b3 = r3[64 + lane];
    f4 c3 = r3[128 + lane],             d3 = r3[192 + lane];

    float dot[4];
    {
        f4 t0 = a0 * va + b0 * vb + c0 * vc + d0 * vd;
        dot[0] = t0.x + t0.y + t0.z + t0.w;
        f4 t1 = a1 * va + b1 * vb + c1 * vc + d1 * vd;
        dot[1] = t1.x + t1.y + t1.z + t1.w;
        f4 t2 = a2 * va + b2 * vb + c2 * vc + d2 * vd;
        dot[2] = t2.x + t2.y + t2.z + t2.w;
        f4 t3 = a3 * va + b3 * vb + c3 * vc + d3 * vd;
        dot[3] = t3.x + t3.y + t3.z + t3.w;
    }

    // 4 interleaved butterfly reductions (all lanes end with full sums)
#pragma unroll
    for (int off = 32; off > 0; off >>= 1) {
#pragma unroll
        for (int r = 0; r < 4; ++r) dot[r] += __shfl_xor(dot[r], off, 64);
    }

    if (lane == 0) {
        float4 e = make_float4(dot[0], dot[1], dot[2], dot[3]);
        *(float4*)(energies + s0) = e;
    }

    float m = fmaxf(fmaxf(dot[0], dot[1]), fmaxf(dot[2], dot[3]));
    float sum = __expf(dot[0] - m) + __expf(dot[1] - m) +
                __expf(dot[2] - m) + __expf(dot[3] - m);

    __shared__ float wm[4], wsum[4];
    if (lane == 0) { wm[wave] = m; wsum[wave] = sum; }
    __syncthreads();
    if (threadIdx.x == 0) {
        float M = wm[0], Sm = wsum[0];
#pragma unroll
        for (int w = 1; w < 4; ++w) {
            float Mn = fmaxf(M, wm[w]);
            Sm = Sm * __expf(M - Mn) + wsum[w] * __expf(wm[w] - Mn);
            M = Mn;
        }
        pmax[blockIdx.x] = M;
        psum[blockIdx.x] = Sm;
    }
}

// K3: combine 2048 block partials -> M, invSum. Single block of 1024,
// shuffle-based (2 sync points).
__global__ __launch_bounds__(1024) void combine(const float* __restrict__ pmax,
                                                const float* __restrict__ psum,
                                                float* __restrict__ MS) {
    const int tid = threadIdx.x;
    const int lane = tid & 63;
    const int wave = tid >> 6;

    float m1 = pmax[tid], s1 = psum[tid];
    float m2 = pmax[tid + 1024], s2 = psum[tid + 1024];
    float M = fmaxf(m1, m2);
    float Sv = s1 * __expf(m1 - M) + s2 * __expf(m2 - M);

#pragma unroll
    for (int off = 32; off > 0; off >>= 1) {
        float Mo = __shfl_xor(M, off, 64);
        float So = __shfl_xor(Sv, off, 64);
        float Mn = fmaxf(M, Mo);
        Sv = Sv * __expf(M - Mn) + So * __expf(Mo - Mn);
        M = Mn;
    }

    __shared__ float sm[16], ss[16];
    if (lane == 0) { sm[wave] = M; ss[wave] = Sv; }
    __syncthreads();
    if (wave == 0) {
        float Mv = (lane < 16) ? sm[lane] : -INFINITY;
        float Sw = (lane < 16) ? ss[lane] : 0.f;
#pragma unroll
        for (int off = 8; off > 0; off >>= 1) {
            float Mo = __shfl_xor(Mv, off, 64);
            float So = __shfl_xor(Sw, off, 64);
            float Mn = fmaxf(Mv, Mo);
            Sw = Sw * __expf(Mv - Mn) + So * __expf(Mo - Mn);
            Mv = Mn;
        }
        if (lane == 0) {
            MS[0] = Mv;
            MS[1] = 1.0f / Sw;
        }
    }
}

// K4: out[i] = exp(e[i]-M) * invSum, in-place on d_out, float4.
__global__ __launch_bounds__(256) void finalize(float* __restrict__ out,
                                                const float* __restrict__ MS) {
    int i = blockIdx.x * 256 + threadIdx.x;
    float M = MS[0];
    float inv = MS[1];
    float4 e = ((const float4*)out)[i];
    float4 o;
    o.x = __expf(e.x - M) * inv;
    o.y = __expf(e.y - M) * inv;
    o.z = __expf(e.z - M) * inv;
    o.w = __expf(e.w - M) * inv;
    ((float4*)out)[i] = o;
}

extern "C" void kernel_launch(void* const* d_in, const int* in_sizes, int n_in,
                              void* d_out, int out_size, void* d_ws, size_t ws_size,
                              hipStream_t stream) {
    const float* hidden = (const float*)d_in[0];   // [H]
    const float* enc    = (const float*)d_in[1];   // [S,H]
    const float* W      = (const float*)d_in[2];   // [H,H]
    // d_in[3] = b: softmax is shift-invariant -> b contributes a constant, skip it.

    float* ws   = (float*)d_ws;
    float* v    = ws;          // 1024
    float* pmax = ws + 1024;   // 2048
    float* psum = ws + 3072;   // 2048
    float* MS   = ws + 5120;   // 2
    float* out  = (float*)d_out;  // energies scratch, then probabilities

    hipMemsetAsync(v, 0, H * sizeof(float), stream);
    compute_v<<<dim3(4, 64), 256, 0, stream>>>(W, hidden, v);
    energies_kernel<<<S / 16, 256, 0, stream>>>(enc, v, out, pmax, psum);
    combine<<<1, 1024, 0, stream>>>(pmax, psum, MS);
    finalize<<<S / 4 / 256, 256, 0, stream>>>(out, MS);
}